// Round 1
// baseline (55.474 us; speedup 1.0000x reference)
//
#include <hip/hip_runtime.h>

// Problem constants (from reference setup_inputs)
constexpr int B = 512;
constexpr int N = 1000;
constexpr int D = 128;
constexpr int F = 2;
constexpr float LN_EPS = 1e-3f;

// One block per batch element. 1024 threads.
// Phase 1: mean over N rows of H[b] (the 262MB streaming read — all threads).
// Phase 2: gather 2 indexed rows + matvec (384->128) + ReLU + LayerNorm (wave 0).
__global__ __launch_bounds__(1024) void fused_gather_mean_dense_ln(
    const float* __restrict__ H, const int* __restrict__ indice,
    const float* __restrict__ W, const float* __restrict__ bias,
    const float* __restrict__ gamma, const float* __restrict__ beta,
    float* __restrict__ out)
{
    const int b   = blockIdx.x;
    const int tid = threadIdx.x;
    const float* __restrict__ Hb = H + (size_t)b * (N * D);

    __shared__ float  semb[(F + 1) * D];   // 384 floats: [row_i0 | row_i1 | mean]
    __shared__ float4 spart[32][32];       // 16 KiB partial column sums

    // ---- phase 1: column sums over N rows (all 1024 threads) ----
    const int c4 = tid & 31;   // which float4 of a 128-float row
    const int rg = tid >> 5;   // row group 0..31
    float4 acc = make_float4(0.f, 0.f, 0.f, 0.f);
    #pragma unroll 4
    for (int n = rg; n < N; n += 32) {
        const float4 v = *reinterpret_cast<const float4*>(Hb + n * D + c4 * 4);
        acc.x += v.x; acc.y += v.y; acc.z += v.z; acc.w += v.w;
    }
    spart[rg][c4] = acc;

    // gather the two indexed rows concurrently (threads 0..63)
    if (tid < 64) {
        const int f   = tid >> 5;              // 0 or 1
        const int idx = indice[b * F + f];     // in [0, N)
        const float4 v = *reinterpret_cast<const float4*>(Hb + idx * D + c4 * 4);
        *reinterpret_cast<float4*>(&semb[f * D + c4 * 4]) = v;
    }
    __syncthreads();

    // ---- combine 32 row-group partials -> mean row (threads 0..31) ----
    if (tid < 32) {
        float4 s = spart[0][tid];
        #pragma unroll
        for (int g = 1; g < 32; ++g) {
            const float4 p = spart[g][tid];
            s.x += p.x; s.y += p.y; s.z += p.z; s.w += p.w;
        }
        const float inv = 1.0f / (float)N;
        *reinterpret_cast<float4*>(&semb[2 * D + tid * 4]) =
            make_float4(s.x * inv, s.y * inv, s.z * inv, s.w * inv);
    }
    __syncthreads();

    // ---- phase 2: dense (384 -> 128) + ReLU + LayerNorm (wave 0, lanes 0..31) ----
    if (tid < 32) {
        const float4* __restrict__ W4 = reinterpret_cast<const float4*>(W);
        float4 x = reinterpret_cast<const float4*>(bias)[tid];
        for (int k = 0; k < (F + 1) * D; ++k) {
            const float  e = semb[k];              // LDS broadcast (free)
            const float4 w = W4[k * 32 + tid];     // coalesced, L2-hot
            x.x = fmaf(e, w.x, x.x);
            x.y = fmaf(e, w.y, x.y);
            x.z = fmaf(e, w.z, x.z);
            x.w = fmaf(e, w.w, x.w);
        }
        x.x = fmaxf(x.x, 0.f); x.y = fmaxf(x.y, 0.f);
        x.z = fmaxf(x.z, 0.f); x.w = fmaxf(x.w, 0.f);

        // LayerNorm over 128 values held as 32 lanes x float4 (single wave)
        float s  = x.x + x.y + x.z + x.w;
        float s2 = x.x * x.x + x.y * x.y + x.z * x.z + x.w * x.w;
        #pragma unroll
        for (int off = 1; off < 32; off <<= 1) {
            s  += __shfl_xor(s,  off);
            s2 += __shfl_xor(s2, off);
        }
        const float mean = s  * (1.0f / (float)D);
        const float var  = s2 * (1.0f / (float)D) - mean * mean;
        const float rstd = rsqrtf(var + LN_EPS);

        const float4 g4 = reinterpret_cast<const float4*>(gamma)[tid];
        const float4 b4 = reinterpret_cast<const float4*>(beta)[tid];
        float4 y;
        y.x = g4.x * (x.x - mean) * rstd + b4.x;
        y.y = g4.y * (x.y - mean) * rstd + b4.y;
        y.z = g4.z * (x.z - mean) * rstd + b4.z;
        y.w = g4.w * (x.w - mean) * rstd + b4.w;
        reinterpret_cast<float4*>(out)[b * 32 + tid] = y;
    }
}

extern "C" void kernel_launch(void* const* d_in, const int* in_sizes, int n_in,
                              void* d_out, int out_size, void* d_ws, size_t ws_size,
                              hipStream_t stream) {
    const float* H      = (const float*)d_in[0];
    const int*   indice = (const int*)  d_in[1];
    const float* W      = (const float*)d_in[2];
    const float* bias   = (const float*)d_in[3];
    const float* gamma  = (const float*)d_in[4];
    const float* beta   = (const float*)d_in[5];
    float* out = (float*)d_out;

    fused_gather_mean_dense_ln<<<dim3(B), dim3(1024), 0, stream>>>(
        H, indice, W, bias, gamma, beta, out);
}

// Round 3
// 50.833 us; speedup vs baseline: 1.0913x; 1.0913x over previous
//
#include <hip/hip_runtime.h>

// Problem constants (from reference setup_inputs)
constexpr int B = 512;
constexpr int N = 1000;    // rows per batch
constexpr int D = 128;
constexpr int F = 2;
constexpr float LN_EPS = 1e-3f;

constexpr int CHUNKS = 4;          // row-chunks per batch for kernel A
constexpr int ROWS_PER_CHUNK = N / CHUNKS;  // 250

// clang-native 4-float vector (accepted by __builtin_nontemporal_load)
typedef float fx4 __attribute__((ext_vector_type(4)));

// ---------------- Kernel A: streaming column sums ----------------
// grid = B*CHUNKS = 2048 blocks, 256 threads. Each block sums 250 rows
// (125 KB contiguous) of one batch into ws[(b*CHUNKS+ch)*32 + c4] (fx4).
__global__ __launch_bounds__(256) void colsum_kernel(
    const float* __restrict__ H, fx4* __restrict__ ws)
{
    const int blk = blockIdx.x;
    const int b   = blk >> 2;          // batch
    const int ch  = blk & 3;           // chunk
    const int tid = threadIdx.x;
    const int c4  = tid & 31;          // which fx4 of the 128-float row
    const int rg  = tid >> 5;          // row group 0..7

    const float* __restrict__ Hb = H + (size_t)b * (N * D);
    const int nstart = ch * ROWS_PER_CHUNK;
    const int nend   = nstart + ROWS_PER_CHUNK;

    fx4 acc = (fx4)(0.f);
    #pragma unroll 4
    for (int n = nstart + rg; n < nend; n += 8) {
        const fx4 v = __builtin_nontemporal_load(
            reinterpret_cast<const fx4*>(Hb + n * D + c4 * 4));
        acc += v;
    }

    __shared__ fx4 sp[8][32];
    sp[rg][c4] = acc;
    __syncthreads();

    if (tid < 32) {
        fx4 s = sp[0][tid];
        #pragma unroll
        for (int g = 1; g < 8; ++g) s += sp[g][tid];
        ws[(size_t)(b * CHUNKS + ch) * 32 + tid] = s;
    }
}

// ---------------- Kernel B: gather + dense + ReLU + LayerNorm ----------------
// grid = B blocks, 128 threads (2 waves). Thread o owns output element o.
__global__ __launch_bounds__(128) void gather_dense_ln(
    const float* __restrict__ H, const int* __restrict__ indice,
    const float* __restrict__ ws, const float* __restrict__ W,
    const float* __restrict__ bias, const float* __restrict__ gamma,
    const float* __restrict__ beta, float* __restrict__ out)
{
    const int b = blockIdx.x;
    const int o = threadIdx.x;   // 0..127

    __shared__ float semb[(F + 1) * D];  // [row_i0 | row_i1 | mean]
    __shared__ float sred[2], sred2[2];

    const float* __restrict__ Hb = H + (size_t)b * (N * D);
    const int i0 = indice[b * F + 0];
    const int i1 = indice[b * F + 1];
    semb[o]       = Hb[i0 * D + o];
    semb[D + o]   = Hb[i1 * D + o];
    const float cs = ws[(size_t)(b * CHUNKS + 0) * D + o]
                   + ws[(size_t)(b * CHUNKS + 1) * D + o]
                   + ws[(size_t)(b * CHUNKS + 2) * D + o]
                   + ws[(size_t)(b * CHUNKS + 3) * D + o];
    semb[2 * D + o] = cs * (1.0f / (float)N);
    __syncthreads();

    // matvec: x[o] = sum_k emb[k] * W[k,o], 4 independent accumulators
    float x0 = bias[o], x1 = 0.f, x2 = 0.f, x3 = 0.f;
    #pragma unroll 8
    for (int k = 0; k < (F + 1) * D; k += 4) {
        x0 = fmaf(semb[k + 0], W[(k + 0) * D + o], x0);
        x1 = fmaf(semb[k + 1], W[(k + 1) * D + o], x1);
        x2 = fmaf(semb[k + 2], W[(k + 2) * D + o], x2);
        x3 = fmaf(semb[k + 3], W[(k + 3) * D + o], x3);
    }
    float x = fmaxf((x0 + x1) + (x2 + x3), 0.f);

    // LayerNorm over 128 values held one-per-thread across 2 waves
    float s = x, s2 = x * x;
    #pragma unroll
    for (int off = 1; off < 64; off <<= 1) {
        s  += __shfl_xor(s,  off);
        s2 += __shfl_xor(s2, off);
    }
    const int wid = o >> 6;
    if ((o & 63) == 0) { sred[wid] = s; sred2[wid] = s2; }
    __syncthreads();
    const float S  = sred[0]  + sred[1];
    const float S2 = sred2[0] + sred2[1];
    const float mean = S * (1.0f / (float)D);
    const float var  = S2 * (1.0f / (float)D) - mean * mean;
    const float rstd = rsqrtf(var + LN_EPS);

    out[(size_t)b * D + o] = gamma[o] * (x - mean) * rstd + beta[o];
}

extern "C" void kernel_launch(void* const* d_in, const int* in_sizes, int n_in,
                              void* d_out, int out_size, void* d_ws, size_t ws_size,
                              hipStream_t stream) {
    const float* H      = (const float*)d_in[0];
    const int*   indice = (const int*)  d_in[1];
    const float* W      = (const float*)d_in[2];
    const float* bias   = (const float*)d_in[3];
    const float* gamma  = (const float*)d_in[4];
    const float* beta   = (const float*)d_in[5];
    float* out = (float*)d_out;
    float* ws  = (float*)d_ws;   // needs B*CHUNKS*D floats = 1 MB

    colsum_kernel<<<dim3(B * CHUNKS), dim3(256), 0, stream>>>(
        H, reinterpret_cast<fx4*>(ws));
    gather_dense_ln<<<dim3(B), dim3(128), 0, stream>>>(
        H, indice, ws, W, bias, gamma, beta, out);
}